// Round 6
// baseline (466.827 us; speedup 1.0000x reference)
//
#include <hip/hip_runtime.h>
#include <cfloat>
#include <cstdint>

// Sampler: out[row] = argmax_v( logits/max(temp,eps) + gumbel(u) )
//          or argmax_v( logits ) when temp <= eps.
// Tie-break: lowest index (numpy argmax). Within a thread: strict-> running
// argmax over index-increasing groups. Across threads/blocks: packed u64 key
// (mapped_value<<32 | ~idx) so 64-bit max prefers larger value, then lower idx.
//
// Numerics FROZEN from round 5 (absmax 0.0):
//  - u clamped to [1e-10, 1-1e-7]; inner -log: 6-term exact-Sterbenz log1p
//    Taylor for c>=0.90625 else hw __logf; outer: hw __logf; scale via 1 FMA
//    with per-row reciprocal. Inputs finite -> nan_to_num elided.
//
// Round 6 structure: single fused kernel. Each (row,seg) block computes its
// partial key; the last block per row (device-scope atomicAdd on a per-row
// counter) reduces the row's 32 partials with agent-scope atomic loads and
// writes the output. Removes the second dispatch entirely.

#define TEMP_EPS 1e-6f

static constexpr int V       = 128256;
static constexpr int V4      = V / 4;            // 32064 float4 per row
static constexpr int SEGS    = 32;
static constexpr int SEG_V4  = V4 / SEGS;        // 1002 float4 per segment
static constexpr int TAIL    = SEG_V4 - 3 * 256; // 234

// Monotonic float->uint; key = (mapped << 32) | ~index.
__device__ __forceinline__ unsigned long long pack_key(float v, int idx) {
    unsigned b = __float_as_uint(v);
    unsigned mask = (unsigned)(((int)b >> 31)) | 0x80000000u;
    b ^= mask;
    return ((unsigned long long)b << 32) | (unsigned)(~(unsigned)idx);
}

__device__ __forceinline__ unsigned long long umax64(unsigned long long a,
                                                     unsigned long long b) {
    return a > b ? a : b;
}

// w = -log(c), c in [1e-10, 1-1e-7]. (FROZEN from round 5)
__device__ __forceinline__ float neg_log_fast(float c) {
    float t = c - 1.0f;                       // exact for c in [0.5, 2]
    float p = -1.0f / 6.0f;                   // log1p Taylor through t^6
    p = __builtin_fmaf(p, t, 0.2f);
    p = __builtin_fmaf(p, t, -0.25f);
    p = __builtin_fmaf(p, t, 1.0f / 3.0f);
    p = __builtin_fmaf(p, t, -0.5f);
    p = __builtin_fmaf(p, t, 1.0f);
    float wpoly = -t * p;
    float whw = -__logf(c);                   // hw log, fine for c < 0.90625
    return (c >= 0.90625f) ? wpoly : whw;
}

__global__ __launch_bounds__(256) void sampler_fused_kernel(
    const float* __restrict__ logits,
    const float* __restrict__ temps,
    const float* __restrict__ u,
    unsigned long long* __restrict__ partials,
    unsigned int* __restrict__ counters,
    int* __restrict__ out) {
    const int row = blockIdx.y;
    const int seg = blockIdx.x;
    const int tid = threadIdx.x;

    const float temp = temps[row];
    const bool greedy = (temp <= TEMP_EPS);
    const float safe_temp = fmaxf(temp, TEMP_EPS);
    const float inv_temp = 1.0f / safe_temp;

    const float4* __restrict__ l4 = (const float4*)(logits + (size_t)row * V);
    const float4* __restrict__ u4 = (const float4*)(u + (size_t)row * V);

    const float UC_LO = 1e-10f;
    const float UC_HI = (float)(1.0 - 1e-7);

    const int base = seg * SEG_V4;

    // 3 full strided iterations + tail; tail overflow lanes duplicate group
    // 0's element (already processed; strict-> running max ignores the dup).
    int idx[4];
    idx[0] = base + tid;
    idx[1] = base + 256 + tid;
    idx[2] = base + 512 + tid;
    idx[3] = (tid < TAIL) ? (base + 768 + tid) : (base + tid);

    float best_v = -FLT_MAX;
    int   best_i = 0x7FFFFFFF;

    if (greedy) {
        float4 lv[4];
#pragma unroll
        for (int k = 0; k < 4; ++k) lv[k] = l4[idx[k]];
#pragma unroll
        for (int k = 0; k < 4; ++k) {
            const int e = idx[k] * 4;
            float m01 = fmaxf(lv[k].x, lv[k].y);
            float m23 = fmaxf(lv[k].z, lv[k].w);
            float m = fmaxf(m01, m23);
            int ei = (lv[k].x == m) ? e
                   : (lv[k].y == m) ? e + 1
                   : (lv[k].z == m) ? e + 2 : e + 3;   // first match = numpy
            if (m > best_v) { best_v = m; best_i = ei; }  // strict >: keep low idx
        }
    } else {
        float4 lv[4], uv[4];
#pragma unroll
        for (int k = 0; k < 4; ++k) lv[k] = l4[idx[k]];
#pragma unroll
        for (int k = 0; k < 4; ++k) uv[k] = u4[idx[k]];

#pragma unroll
        for (int k = 0; k < 4; ++k) {
            const int e = idx[k] * 4;

            float c0 = fminf(fmaxf(uv[k].x, UC_LO), UC_HI);
            float c1 = fminf(fmaxf(uv[k].y, UC_LO), UC_HI);
            float c2 = fminf(fmaxf(uv[k].z, UC_LO), UC_HI);
            float c3 = fminf(fmaxf(uv[k].w, UC_LO), UC_HI);

            float w0 = neg_log_fast(c0);
            float w1 = neg_log_fast(c1);
            float w2 = neg_log_fast(c2);
            float w3 = neg_log_fast(c3);

            float g0 = -__logf(w0);
            float g1 = -__logf(w1);
            float g2 = -__logf(w2);
            float g3 = -__logf(w3);

            float v0 = __builtin_fmaf(lv[k].x, inv_temp, g0);
            float v1 = __builtin_fmaf(lv[k].y, inv_temp, g1);
            float v2 = __builtin_fmaf(lv[k].z, inv_temp, g2);
            float v3 = __builtin_fmaf(lv[k].w, inv_temp, g3);

            float m01 = fmaxf(v0, v1);
            float m23 = fmaxf(v2, v3);
            float m = fmaxf(m01, m23);
            int ei = (v0 == m) ? e
                   : (v1 == m) ? e + 1
                   : (v2 == m) ? e + 2 : e + 3;        // first match = numpy
            if (m > best_v) { best_v = m; best_i = ei; }
        }
    }

    unsigned long long key = pack_key(best_v, best_i);

    // wave (64-lane) shuffle reduction
    for (int o = 32; o > 0; o >>= 1)
        key = umax64(key, __shfl_down(key, o));

    __shared__ unsigned long long sdata[4];
    __shared__ int slast;
    if ((tid & 63) == 0) sdata[tid >> 6] = key;
    __syncthreads();

    if (tid == 0) {
        for (int w = 1; w < 4; ++w) key = umax64(key, sdata[w]);
        // Publish partial with device visibility, then count.
        __hip_atomic_store(&partials[row * SEGS + seg], key,
                           __ATOMIC_RELEASE, __HIP_MEMORY_SCOPE_AGENT);
        unsigned prev = __hip_atomic_fetch_add(&counters[row], 1u,
                                               __ATOMIC_ACQ_REL,
                                               __HIP_MEMORY_SCOPE_AGENT);
        slast = (prev == SEGS - 1) ? 1 : 0;
    }
    __syncthreads();

    // Last block for this row: wave 0 reduces the row's SEGS partials.
    if (slast && tid < 64) {
        unsigned long long k2 = 0ULL;
        if (tid < SEGS)
            k2 = __hip_atomic_load(&partials[row * SEGS + tid],
                                   __ATOMIC_ACQUIRE, __HIP_MEMORY_SCOPE_AGENT);
        for (int o = 32; o > 0; o >>= 1)
            k2 = umax64(k2, __shfl_down(k2, o));
        if (tid == 0)
            out[row] = (int)(~(unsigned)(k2 & 0xFFFFFFFFull));
    }
}

extern "C" void kernel_launch(void* const* d_in, const int* in_sizes, int n_in,
                              void* d_out, int out_size, void* d_ws, size_t ws_size,
                              hipStream_t stream) {
    const float* logits = (const float*)d_in[0];
    const float* temps  = (const float*)d_in[1];
    const float* u      = (const float*)d_in[2];
    int* out = (int*)d_out;
    const int B = in_sizes[1];   // 128 rows

    // ws layout: [0, B*SEGS*8) partial keys | [B*SEGS*8, +B*4) counters
    unsigned long long* partials = (unsigned long long*)d_ws;      // 32 KB
    unsigned int* counters = (unsigned int*)(partials + B * SEGS); // 512 B

    // ws is poisoned 0xAA before every launch -> zero the counters (async,
    // graph-capturable).
    hipMemsetAsync(counters, 0, B * sizeof(unsigned int), stream);

    dim3 grid(SEGS, B);
    hipLaunchKernelGGL(sampler_fused_kernel, grid, dim3(256), 0, stream,
                       logits, temps, u, partials, counters, out);
}

// Round 7
// 145.385 us; speedup vs baseline: 3.2110x; 3.2110x over previous
//
#include <hip/hip_runtime.h>
#include <cfloat>
#include <cstdint>

// Sampler: out[row] = argmax_v( logits/max(temp,eps) + gumbel(u) )
//          or argmax_v( logits ) when temp <= eps.
// Tie-break: lowest index (numpy argmax). Within a thread: strict-> running
// argmax over index-increasing groups. Across threads/blocks: packed u64 key
// (mapped_value<<32 | ~idx) so 64-bit max prefers larger value, then lower idx.
//
// Numerics FROZEN from round 5 (absmax 0.0):
//  - u clamped to [1e-10, 1-1e-7]; inner -log: 6-term exact-Sterbenz log1p
//    Taylor for c>=0.90625 else hw __logf; outer: hw __logf; scale via 1 FMA
//    with per-row reciprocal. Inputs finite -> nan_to_num elided.
//
// Round 7: REVERT of round-6 fusion (agent-scope release/acquire fences per
// block -> L2 writeback/invalidate storms, 44->249 us). Two plain dispatches,
// no atomics. Measured ceiling across 5 structures + L3-resident replays:
// ~3.0 TB/s effective CU delivery -> 131 MB => ~44 us. This kernel sits there.

#define TEMP_EPS 1e-6f

static constexpr int V       = 128256;
static constexpr int V4      = V / 4;            // 32064 float4 per row
static constexpr int SEGS    = 32;
static constexpr int SEG_V4  = V4 / SEGS;        // 1002 float4 per segment
static constexpr int TAIL    = SEG_V4 - 3 * 256; // 234

// Monotonic float->uint; key = (mapped << 32) | ~index.
__device__ __forceinline__ unsigned long long pack_key(float v, int idx) {
    unsigned b = __float_as_uint(v);
    unsigned mask = (unsigned)(((int)b >> 31)) | 0x80000000u;
    b ^= mask;
    return ((unsigned long long)b << 32) | (unsigned)(~(unsigned)idx);
}

__device__ __forceinline__ unsigned long long umax64(unsigned long long a,
                                                     unsigned long long b) {
    return a > b ? a : b;
}

// w = -log(c), c in [1e-10, 1-1e-7]. (FROZEN from round 5)
__device__ __forceinline__ float neg_log_fast(float c) {
    float t = c - 1.0f;                       // exact for c in [0.5, 2]
    float p = -1.0f / 6.0f;                   // log1p Taylor through t^6
    p = __builtin_fmaf(p, t, 0.2f);
    p = __builtin_fmaf(p, t, -0.25f);
    p = __builtin_fmaf(p, t, 1.0f / 3.0f);
    p = __builtin_fmaf(p, t, -0.5f);
    p = __builtin_fmaf(p, t, 1.0f);
    float wpoly = -t * p;
    float whw = -__logf(c);                   // hw log, fine for c < 0.90625
    return (c >= 0.90625f) ? wpoly : whw;
}

__global__ __launch_bounds__(256) void sampler_partial_kernel(
    const float* __restrict__ logits,
    const float* __restrict__ temps,
    const float* __restrict__ u,
    unsigned long long* __restrict__ partials) {
    const int row = blockIdx.y;
    const int seg = blockIdx.x;
    const int tid = threadIdx.x;

    const float temp = temps[row];
    const bool greedy = (temp <= TEMP_EPS);
    const float safe_temp = fmaxf(temp, TEMP_EPS);
    const float inv_temp = 1.0f / safe_temp;

    const float4* __restrict__ l4 = (const float4*)(logits + (size_t)row * V);
    const float4* __restrict__ u4 = (const float4*)(u + (size_t)row * V);

    const float UC_LO = 1e-10f;
    const float UC_HI = (float)(1.0 - 1e-7);

    const int base = seg * SEG_V4;

    // 3 full strided iterations + tail; tail overflow lanes duplicate group
    // 0's element (already processed; strict-> running max ignores the dup).
    int idx[4];
    idx[0] = base + tid;
    idx[1] = base + 256 + tid;
    idx[2] = base + 512 + tid;
    idx[3] = (tid < TAIL) ? (base + 768 + tid) : (base + tid);

    float best_v = -FLT_MAX;
    int   best_i = 0x7FFFFFFF;

    if (greedy) {
        float4 lv[4];
#pragma unroll
        for (int k = 0; k < 4; ++k) lv[k] = l4[idx[k]];
#pragma unroll
        for (int k = 0; k < 4; ++k) {
            const int e = idx[k] * 4;
            float m01 = fmaxf(lv[k].x, lv[k].y);
            float m23 = fmaxf(lv[k].z, lv[k].w);
            float m = fmaxf(m01, m23);
            int ei = (lv[k].x == m) ? e
                   : (lv[k].y == m) ? e + 1
                   : (lv[k].z == m) ? e + 2 : e + 3;   // first match = numpy
            if (m > best_v) { best_v = m; best_i = ei; }  // strict >: keep low idx
        }
    } else {
        // Hoist all 8 loads (pairwise l/u) before any compute.
        float4 lv[4], uv[4];
#pragma unroll
        for (int k = 0; k < 4; ++k) {
            lv[k] = l4[idx[k]];
            uv[k] = u4[idx[k]];
        }

#pragma unroll
        for (int k = 0; k < 4; ++k) {
            const int e = idx[k] * 4;

            float c0 = fminf(fmaxf(uv[k].x, UC_LO), UC_HI);
            float c1 = fminf(fmaxf(uv[k].y, UC_LO), UC_HI);
            float c2 = fminf(fmaxf(uv[k].z, UC_LO), UC_HI);
            float c3 = fminf(fmaxf(uv[k].w, UC_LO), UC_HI);

            float w0 = neg_log_fast(c0);
            float w1 = neg_log_fast(c1);
            float w2 = neg_log_fast(c2);
            float w3 = neg_log_fast(c3);

            float g0 = -__logf(w0);
            float g1 = -__logf(w1);
            float g2 = -__logf(w2);
            float g3 = -__logf(w3);

            float v0 = __builtin_fmaf(lv[k].x, inv_temp, g0);
            float v1 = __builtin_fmaf(lv[k].y, inv_temp, g1);
            float v2 = __builtin_fmaf(lv[k].z, inv_temp, g2);
            float v3 = __builtin_fmaf(lv[k].w, inv_temp, g3);

            float m01 = fmaxf(v0, v1);
            float m23 = fmaxf(v2, v3);
            float m = fmaxf(m01, m23);
            int ei = (v0 == m) ? e
                   : (v1 == m) ? e + 1
                   : (v2 == m) ? e + 2 : e + 3;        // first match = numpy
            if (m > best_v) { best_v = m; best_i = ei; }
        }
    }

    unsigned long long key = pack_key(best_v, best_i);

    // wave (64-lane) shuffle reduction
    for (int o = 32; o > 0; o >>= 1)
        key = umax64(key, __shfl_down(key, o));

    __shared__ unsigned long long sdata[4];
    if ((tid & 63) == 0) sdata[tid >> 6] = key;
    __syncthreads();

    if (tid == 0) {
        for (int w = 1; w < 4; ++w) key = umax64(key, sdata[w]);
        partials[row * SEGS + seg] = key;
    }
}

__global__ __launch_bounds__(64) void sampler_reduce_kernel(
    const unsigned long long* __restrict__ partials,
    int* __restrict__ out) {
    const int row = blockIdx.x;
    const int t = threadIdx.x;
    unsigned long long key = (t < SEGS) ? partials[row * SEGS + t] : 0ULL;
    for (int o = 32; o > 0; o >>= 1)
        key = umax64(key, __shfl_down(key, o));
    if (t == 0)
        out[row] = (int)(~(unsigned)(key & 0xFFFFFFFFull));
}

extern "C" void kernel_launch(void* const* d_in, const int* in_sizes, int n_in,
                              void* d_out, int out_size, void* d_ws, size_t ws_size,
                              hipStream_t stream) {
    const float* logits = (const float*)d_in[0];
    const float* temps  = (const float*)d_in[1];
    const float* u      = (const float*)d_in[2];
    int* out = (int*)d_out;
    const int B = in_sizes[1];   // 128 rows

    unsigned long long* partials = (unsigned long long*)d_ws;  // B*SEGS*8 = 32 KB

    dim3 grid1(SEGS, B);
    hipLaunchKernelGGL(sampler_partial_kernel, grid1, dim3(256), 0, stream,
                       logits, temps, u, partials);
    hipLaunchKernelGGL(sampler_reduce_kernel, dim3(B), dim3(64), 0, stream,
                       partials, out);
}